// Round 5
// baseline (408.708 us; speedup 1.0000x reference)
//
#include <hip/hip_runtime.h>
#include <math.h>

#define B_TOT 4096
#define T_LEN 200
#define C_IN  16
#define HH    112
#define NB    16      // batches per block (= MFMA M)
#define EPS   1e-5f
#define SBLK  256     // stats kernel blocks
#define L2E   1.4426950408889634f

typedef _Float16 half8  __attribute__((ext_vector_type(8)));
typedef _Float16 half4v __attribute__((ext_vector_type(4)));
typedef float    f32x4  __attribute__((ext_vector_type(4)));

// Split fp32 into fp16 hi + 2^12-scaled fp16 lo. Flush hi if it would be a
// fp16 denormal (MFMA denormal behavior unverified); lo then carries the value.
__device__ __forceinline__ void split16(float v, _Float16 &hi, _Float16 &lo) {
    _Float16 h = (_Float16)v;
    float hf = (float)h;
    if (__builtin_fabsf(hf) < 6.103515625e-05f) { h = (_Float16)0.0f; hf = 0.0f; }
    hi = h;
    lo = (_Float16)((v - hf) * 4096.0f);
}

// ---------------- Kernel 1: deterministic per-channel partial sums ----------------
__global__ void stats_kernel(const float* __restrict__ x, float* __restrict__ ws) {
    __shared__ float sm[4][4][8];
    const int tid = threadIdx.x;
    const float4* __restrict__ x4 = (const float4*)x;
    const int total  = B_TOT * T_LEN * C_IN / 4;
    const int stride = SBLK * 256;
    const int i0 = blockIdx.x * 256 + tid;

    float s0=0.f,s1=0.f,s2=0.f,s3=0.f;
    float q0=0.f,q1=0.f,q2=0.f,q3=0.f;
    for (int i = i0; i < total; i += stride) {
        float4 v = x4[i];
        s0 += v.x; q0 += v.x*v.x;
        s1 += v.y; q1 += v.y*v.y;
        s2 += v.z; q2 += v.z*v.z;
        s3 += v.w; q3 += v.w*v.w;
    }
    #pragma unroll
    for (int off = 4; off < 64; off <<= 1) {
        s0 += __shfl_xor(s0, off); q0 += __shfl_xor(q0, off);
        s1 += __shfl_xor(s1, off); q1 += __shfl_xor(q1, off);
        s2 += __shfl_xor(s2, off); q2 += __shfl_xor(q2, off);
        s3 += __shfl_xor(s3, off); q3 += __shfl_xor(q3, off);
    }
    const int lane = tid & 63, wave = tid >> 6;
    if (lane < 4) {
        sm[wave][lane][0] = s0; sm[wave][lane][1] = s1;
        sm[wave][lane][2] = s2; sm[wave][lane][3] = s3;
        sm[wave][lane][4] = q0; sm[wave][lane][5] = q1;
        sm[wave][lane][6] = q2; sm[wave][lane][7] = q3;
    }
    __syncthreads();
    if (tid < 32) {
        const int ch = tid & 15, sq = tid >> 4;
        const int grp = ch >> 2, comp = ch & 3;
        float a = 0.f;
        #pragma unroll
        for (int wv = 0; wv < 4; wv++) a += sm[wv][grp][sq * 4 + comp];
        ws[blockIdx.x * 32 + tid] = a;
    }
}

// ---------------- Kernel 2: MFMA LSTM, 14-wave gate-split ----------------
// 256 blocks x 896 threads (14 waves). Wave pair (w, w+7) owns j-tile w:
//   wave w   : gates i (n=0..) and g (n=2H..)  -> 24 MFMAs, computes p = i*g
//   wave w+7 : gates f (n=H..) and o (n=3H..)  -> 24 MFMAs, owns c-state,
//              does the cell update + h write-back.
// p crosses via pbuf (lane-aligned b128). v_t = [h; x] in LDS in A-fragment
// order, double-buffered by step parity (compile-time via unroll 2).
__global__ __launch_bounds__(896, 4) void lstm_kernel(
    const float* __restrict__ x,
    const float* __restrict__ gamma, const float* __restrict__ beta,
    const float* __restrict__ W_ih,  const float* __restrict__ W_hh,
    const float* __restrict__ b_ih,  const float* __restrict__ b_hh,
    const float* __restrict__ W_fc,  const float* __restrict__ b_fc,
    const float* __restrict__ ws,    float* __restrict__ out)
{
    __shared__ float stats_s[32];
    __shared__ float scale_s[16], shift_s[16];
    __shared__ __align__(16) _Float16 vbuf[2][2][4][64][8]; // [plane][hi/lo][kt][lane][8]
    __shared__ __align__(16) float pbuf[7][64][4];          // i*g exchange
    __shared__ __align__(16) float hfinal[NB][HH];

    const int u    = threadIdx.x;
    const int lane = u & 63;
    const int wv   = u >> 6;          // 0..13
    const bool wlow = (wv < 7);
    const int jt   = wlow ? wv : (wv - 7);
    const int nloc = lane & 15;
    const int q    = lane >> 4;       // 0..3
    const int b0   = blockIdx.x * NB;

    // --- BN stats (deterministic fixed-order reduction) ---
    if (u < 32) {
        float a = 0.f;
        for (int blk = 0; blk < SBLK; ++blk) a += ws[blk * 32 + u];
        stats_s[u] = a;
    }
    __syncthreads();
    if (u < 16) {
        const float N = (float)B_TOT * (float)T_LEN;
        const float mean = stats_s[u] / N;
        const float var  = stats_s[16 + u] / N - mean * mean;
        const float sc   = gamma[u] * rsqrtf(var + EPS);
        scale_s[u] = sc;
        shift_s[u] = beta[u] - mean * sc;
    }
    for (int i = u; i < (int)(sizeof(vbuf) / 4); i += 896) ((int*)vbuf)[i] = 0;
    __syncthreads();

    // --- Register-resident weight fragments (2 gates per wave) ---
    const int gate0 = wlow ? 0 : 1;            // i / f
    const int gate1 = wlow ? 2 : 3;            // g / o
    const float mgB = wlow ? 2.f : 1.f;        // gate1 activation: tanh for g
    half8 wHI[2][4], wLO[2][4];
    float bpre[2];
    {
        const int gates[2] = {gate0, gate1};
        const float mgs[2] = {1.f, mgB};
        #pragma unroll
        for (int gg = 0; gg < 2; ++gg) {
            const int n = gates[gg] * HH + jt * 16 + nloc;
            #pragma unroll
            for (int kt = 0; kt < 4; ++kt) {
                const int kb = kt * 32 + q * 8;    // never straddles k=112
                float wtmp[8];
                if (kb < HH) {
                    float4 aa = *(const float4*)&W_hh[n * HH + kb];
                    float4 bb = *(const float4*)&W_hh[n * HH + kb + 4];
                    wtmp[0]=aa.x; wtmp[1]=aa.y; wtmp[2]=aa.z; wtmp[3]=aa.w;
                    wtmp[4]=bb.x; wtmp[5]=bb.y; wtmp[6]=bb.z; wtmp[7]=bb.w;
                } else {
                    const int c0 = kb - HH;
                    float4 aa = *(const float4*)&W_ih[n * C_IN + c0];
                    float4 bb = *(const float4*)&W_ih[n * C_IN + c0 + 4];
                    wtmp[0]=aa.x*scale_s[c0+0]; wtmp[1]=aa.y*scale_s[c0+1];
                    wtmp[2]=aa.z*scale_s[c0+2]; wtmp[3]=aa.w*scale_s[c0+3];
                    wtmp[4]=bb.x*scale_s[c0+4]; wtmp[5]=bb.y*scale_s[c0+5];
                    wtmp[6]=bb.z*scale_s[c0+6]; wtmp[7]=bb.w*scale_s[c0+7];
                }
                #pragma unroll
                for (int jj = 0; jj < 8; ++jj) {
                    _Float16 th, tl;
                    split16(wtmp[jj], th, tl);
                    wHI[gg][kt][jj] = th;
                    wLO[gg][kt][jj] = tl;
                }
            }
            float bb2 = b_ih[n] + b_hh[n];
            #pragma unroll
            for (int c = 0; c < C_IN; ++c) bb2 += W_ih[n * C_IN + c] * shift_s[c];
            bpre[gg] = bb2 * (-mgs[gg] * L2E);
        }
    }

    // --- h write-back mapping (A-fragment address for column jcol) ---
    const int jcol = jt * 16 + nloc;          // 0..111
    const int kt_h = jcol >> 5;
    const int jh   = jcol & 7;
    const int qh16 = ((jcol >> 3) & 3) * 16;  // lane' = b + qh16

    // --- x loader mapping (wave 0): b = u>>2, c = 4*(u&3) ---
    const int xb = u >> 2;
    const int xc = (u & 3) * 4;
    const size_t xbase = (size_t)(b0 + (xb & 15)) * (T_LEN * C_IN) + xc;
    const int jx0 = HH + xc;                  // 112..124
    const int ltx = (xb & 15) + 16 * ((jx0 >> 3) & 3);
    const int jx  = jx0 & 7;

    float4 xreg;
    if (wv == 0) {
        xreg = *(const float4*)&x[xbase];     // x at t=0 -> plane 0
        half4v xh, xl;
        #pragma unroll
        for (int jj = 0; jj < 4; ++jj) {
            _Float16 th, tl;
            split16(((const float*)&xreg)[jj], th, tl);
            xh[jj] = th; xl[jj] = tl;
        }
        *(half4v*)&vbuf[0][0][3][ltx][jx] = xh;
        *(half4v*)&vbuf[0][1][3][ltx][jx] = xl;
    }
    __syncthreads();

    float creg[4] = {0.f, 0.f, 0.f, 0.f};

    const float k1A  = -L2E;
    const float k1As = k1A * (1.f / 4096.f);
    const float k1B  = -mgB * L2E;
    const float k1Bs = k1B * (1.f / 4096.f);
    const float dgB  = 1.f - mgB;

    #pragma unroll 2
    for (int step = 0; step < T_LEN; ++step) {
        const int p = step & 1;
        if (wv == 0 && step + 1 < T_LEN)
            xreg = *(const float4*)&x[xbase + (size_t)(step + 1) * C_IN];

        f32x4 ch0 = {0.f,0.f,0.f,0.f}, cl0 = {0.f,0.f,0.f,0.f};
        f32x4 ch1 = {0.f,0.f,0.f,0.f}, cl1 = {0.f,0.f,0.f,0.f};
        #pragma unroll
        for (int kt = 0; kt < 4; ++kt) {
            half8 ah = *(const half8*)&vbuf[p][0][kt][lane][0];
            half8 al = *(const half8*)&vbuf[p][1][kt][lane][0];
            ch0 = __builtin_amdgcn_mfma_f32_16x16x32_f16(ah, wHI[0][kt], ch0, 0, 0, 0);
            cl0 = __builtin_amdgcn_mfma_f32_16x16x32_f16(al, wHI[0][kt], cl0, 0, 0, 0);
            cl0 = __builtin_amdgcn_mfma_f32_16x16x32_f16(ah, wLO[0][kt], cl0, 0, 0, 0);
            ch1 = __builtin_amdgcn_mfma_f32_16x16x32_f16(ah, wHI[1][kt], ch1, 0, 0, 0);
            cl1 = __builtin_amdgcn_mfma_f32_16x16x32_f16(al, wHI[1][kt], cl1, 0, 0, 0);
            cl1 = __builtin_amdgcn_mfma_f32_16x16x32_f16(ah, wLO[1][kt], cl1, 0, 0, 0);
        }

        // Activations (in-lane): a0 = sigmoid gate (i or f), a1 = g(tanh) or o.
        float a0[4], a1[4];
        #pragma unroll
        for (int r = 0; r < 4; ++r) {
            float aa = fmaf(ch0[r], k1A, bpre[0]);
            aa = fmaf(cl0[r], k1As, aa);
            a0[r] = __builtin_amdgcn_rcpf(1.f + __builtin_amdgcn_exp2f(aa));
            float bb = fmaf(ch1[r], k1B, bpre[1]);
            bb = fmaf(cl1[r], k1Bs, bb);
            a1[r] = fmaf(mgB, __builtin_amdgcn_rcpf(1.f + __builtin_amdgcn_exp2f(bb)), dgB);
        }
        if (wlow) {
            f32x4 pp;
            #pragma unroll
            for (int r = 0; r < 4; ++r) pp[r] = a0[r] * a1[r];   // i*g
            *(f32x4*)&pbuf[jt][lane][0] = pp;
        }
        __syncthreads();

        const bool last = (step + 1 == T_LEN);
        if (!wlow) {
            f32x4 pp = *(const f32x4*)&pbuf[jt][lane][0];
            #pragma unroll
            for (int r = 0; r < 4; ++r) {
                const float cn = fmaf(a0[r], creg[r], pp[r]);   // f*c + i*g
                creg[r] = cn;
                const float e2 = __builtin_amdgcn_exp2f(cn * (-2.f * L2E));
                const float th = fmaf(2.f, __builtin_amdgcn_rcpf(1.f + e2), -1.f);
                const float hv = a1[r] * th;                    // o * tanh(c)
                if (!last) {
                    _Float16 hh, hl;
                    split16(hv, hh, hl);
                    vbuf[1 - p][0][kt_h][q * 4 + r + qh16][jh] = hh;
                    vbuf[1 - p][1][kt_h][q * 4 + r + qh16][jh] = hl;
                } else {
                    hfinal[q * 4 + r][jcol] = hv;
                }
            }
        } else if (wv == 0 && step + 1 < T_LEN) {
            half4v xh, xl;
            #pragma unroll
            for (int jj = 0; jj < 4; ++jj) {
                _Float16 th, tl;
                split16(((const float*)&xreg)[jj], th, tl);
                xh[jj] = th; xl[jj] = tl;
            }
            *(half4v*)&vbuf[1 - p][0][3][ltx][jx] = xh;
            *(half4v*)&vbuf[1 - p][1][3][ltx][jx] = xl;
        }
        __syncthreads();
    }

    // --- FC head ---
    if (u < NB * 6) {
        const int b = u / 6, o = u - b * 6;
        float a = b_fc[o];
        for (int j = 0; j < HH; ++j) a += hfinal[b][j] * W_fc[o * HH + j];
        out[(size_t)(b0 + b) * 6 + o] = tanhf(a);
    }
}

extern "C" void kernel_launch(void* const* d_in, const int* in_sizes, int n_in,
                              void* d_out, int out_size, void* d_ws, size_t ws_size,
                              hipStream_t stream) {
    const float* x     = (const float*)d_in[0];
    const float* gamma = (const float*)d_in[1];
    const float* beta  = (const float*)d_in[2];
    const float* W_ih  = (const float*)d_in[3];
    const float* W_hh  = (const float*)d_in[4];
    const float* b_ih  = (const float*)d_in[5];
    const float* b_hh  = (const float*)d_in[6];
    const float* W_fc  = (const float*)d_in[7];
    const float* b_fc  = (const float*)d_in[8];
    float* out = (float*)d_out;
    float* ws  = (float*)d_ws;

    stats_kernel<<<SBLK, 256, 0, stream>>>(x, ws);
    lstm_kernel<<<B_TOT / NB, 896, 0, stream>>>(x, gamma, beta, W_ih, W_hh,
                                                b_ih, b_hh, W_fc, b_fc, ws, out);
}

// Round 6
// 401.542 us; speedup vs baseline: 1.0178x; 1.0178x over previous
//
#include <hip/hip_runtime.h>
#include <math.h>

#define B_TOT 4096
#define T_LEN 200
#define C_IN  16
#define HH    112
#define NB    16      // batches per block (= MFMA M)
#define EPS   1e-5f
#define SBLK  256     // stats kernel blocks
#define L2E   1.4426950408889634f

typedef _Float16 half8  __attribute__((ext_vector_type(8)));
typedef _Float16 half4v __attribute__((ext_vector_type(4)));
typedef float    f32x4  __attribute__((ext_vector_type(4)));

// Split fp32 into fp16 hi + 2^12-scaled fp16 lo. Flush hi if it would be a
// fp16 denormal (MFMA denormal behavior unverified); lo then carries the value.
__device__ __forceinline__ void split16(float v, _Float16 &hi, _Float16 &lo) {
    _Float16 h = (_Float16)v;
    float hf = (float)h;
    if (__builtin_fabsf(hf) < 6.103515625e-05f) { h = (_Float16)0.0f; hf = 0.0f; }
    hi = h;
    lo = (_Float16)((v - hf) * 4096.0f);
}

// ---------------- Kernel 1: deterministic per-channel partial sums ----------------
__global__ void stats_kernel(const float* __restrict__ x, float* __restrict__ ws) {
    __shared__ float sm[4][4][8];
    const int tid = threadIdx.x;
    const float4* __restrict__ x4 = (const float4*)x;
    const int total  = B_TOT * T_LEN * C_IN / 4;
    const int stride = SBLK * 256;
    const int i0 = blockIdx.x * 256 + tid;

    float s0=0.f,s1=0.f,s2=0.f,s3=0.f;
    float q0=0.f,q1=0.f,q2=0.f,q3=0.f;
    for (int i = i0; i < total; i += stride) {
        float4 v = x4[i];
        s0 += v.x; q0 += v.x*v.x;
        s1 += v.y; q1 += v.y*v.y;
        s2 += v.z; q2 += v.z*v.z;
        s3 += v.w; q3 += v.w*v.w;
    }
    #pragma unroll
    for (int off = 4; off < 64; off <<= 1) {
        s0 += __shfl_xor(s0, off); q0 += __shfl_xor(q0, off);
        s1 += __shfl_xor(s1, off); q1 += __shfl_xor(q1, off);
        s2 += __shfl_xor(s2, off); q2 += __shfl_xor(q2, off);
        s3 += __shfl_xor(s3, off); q3 += __shfl_xor(q3, off);
    }
    const int lane = tid & 63, wave = tid >> 6;
    if (lane < 4) {
        sm[wave][lane][0] = s0; sm[wave][lane][1] = s1;
        sm[wave][lane][2] = s2; sm[wave][lane][3] = s3;
        sm[wave][lane][4] = q0; sm[wave][lane][5] = q1;
        sm[wave][lane][6] = q2; sm[wave][lane][7] = q3;
    }
    __syncthreads();
    if (tid < 32) {
        const int ch = tid & 15, sq = tid >> 4;
        const int grp = ch >> 2, comp = ch & 3;
        float a = 0.f;
        #pragma unroll
        for (int wv = 0; wv < 4; wv++) a += sm[wv][grp][sq * 4 + comp];
        ws[blockIdx.x * 32 + tid] = a;
    }
}

// ---------------- Kernel 2: MFMA LSTM, pairwise-sync gate-split ----------------
// 256 blocks x 896 threads (14 waves). Wave pair (w, w+7) owns j-tile w:
//   wave w   (low) : gates i, g -> 24 MFMAs, p = i*g -> pbuf, flag handshake
//   wave w+7 (high): gates f, o -> 24 MFMAs, spins on flag, owns c-state,
//                    cell update + h write-back.
// ONE full barrier per step (vbuf publish). Pairs drift within the step, so
// one pair's epilogue VALU overlaps another pair's MFMAs on the same SIMD.
__global__ __launch_bounds__(896, 4) void lstm_kernel(
    const float* __restrict__ x,
    const float* __restrict__ gamma, const float* __restrict__ beta,
    const float* __restrict__ W_ih,  const float* __restrict__ W_hh,
    const float* __restrict__ b_ih,  const float* __restrict__ b_hh,
    const float* __restrict__ W_fc,  const float* __restrict__ b_fc,
    const float* __restrict__ ws,    float* __restrict__ out)
{
    __shared__ float stats_s[32];
    __shared__ float scale_s[16], shift_s[16];
    __shared__ __align__(16) _Float16 vbuf[2][2][4][64][8]; // [plane][hi/lo][kt][lane][8]
    __shared__ __align__(16) float pbuf[7][64][4];          // i*g exchange
    __shared__ volatile int sflag[8];                       // pair handshake
    __shared__ __align__(16) float hfinal[NB][HH];

    const int u    = threadIdx.x;
    const int lane = u & 63;
    const int wv   = u >> 6;          // 0..13
    const bool wlow = (wv < 7);
    const int jt   = wlow ? wv : (wv - 7);
    const int nloc = lane & 15;
    const int q    = lane >> 4;       // 0..3
    const int b0   = blockIdx.x * NB;

    // --- BN stats (deterministic fixed-order reduction) ---
    if (u < 32) {
        float a = 0.f;
        for (int blk = 0; blk < SBLK; ++blk) a += ws[blk * 32 + u];
        stats_s[u] = a;
    }
    if (u >= 32 && u < 40) sflag[u - 32] = 0;
    __syncthreads();
    if (u < 16) {
        const float N = (float)B_TOT * (float)T_LEN;
        const float mean = stats_s[u] / N;
        const float var  = stats_s[16 + u] / N - mean * mean;
        const float sc   = gamma[u] * rsqrtf(var + EPS);
        scale_s[u] = sc;
        shift_s[u] = beta[u] - mean * sc;
    }
    for (int i = u; i < (int)(sizeof(vbuf) / 4); i += 896) ((int*)vbuf)[i] = 0;
    __syncthreads();

    // --- Register-resident weight fragments (2 gates per wave) ---
    const int gate0 = wlow ? 0 : 1;            // i / f
    const int gate1 = wlow ? 2 : 3;            // g / o
    half8 wHI[2][4], wLO[2][4];
    float bpre[2];
    {
        const int gates[2] = {gate0, gate1};
        const float mgs[2] = {1.f, wlow ? 2.f : 1.f};
        #pragma unroll
        for (int gg = 0; gg < 2; ++gg) {
            const int n = gates[gg] * HH + jt * 16 + nloc;
            #pragma unroll
            for (int kt = 0; kt < 4; ++kt) {
                const int kb = kt * 32 + q * 8;    // never straddles k=112
                float wtmp[8];
                if (kb < HH) {
                    float4 aa = *(const float4*)&W_hh[n * HH + kb];
                    float4 bb = *(const float4*)&W_hh[n * HH + kb + 4];
                    wtmp[0]=aa.x; wtmp[1]=aa.y; wtmp[2]=aa.z; wtmp[3]=aa.w;
                    wtmp[4]=bb.x; wtmp[5]=bb.y; wtmp[6]=bb.z; wtmp[7]=bb.w;
                } else {
                    const int c0 = kb - HH;
                    float4 aa = *(const float4*)&W_ih[n * C_IN + c0];
                    float4 bb = *(const float4*)&W_ih[n * C_IN + c0 + 4];
                    wtmp[0]=aa.x*scale_s[c0+0]; wtmp[1]=aa.y*scale_s[c0+1];
                    wtmp[2]=aa.z*scale_s[c0+2]; wtmp[3]=aa.w*scale_s[c0+3];
                    wtmp[4]=bb.x*scale_s[c0+4]; wtmp[5]=bb.y*scale_s[c0+5];
                    wtmp[6]=bb.z*scale_s[c0+6]; wtmp[7]=bb.w*scale_s[c0+7];
                }
                #pragma unroll
                for (int jj = 0; jj < 8; ++jj) {
                    _Float16 th, tl;
                    split16(wtmp[jj], th, tl);
                    wHI[gg][kt][jj] = th;
                    wLO[gg][kt][jj] = tl;
                }
            }
            float bb2 = b_ih[n] + b_hh[n];
            #pragma unroll
            for (int c = 0; c < C_IN; ++c) bb2 += W_ih[n * C_IN + c] * shift_s[c];
            bpre[gg] = bb2 * (-mgs[gg] * L2E);
        }
    }

    // --- h write-back mapping (A-fragment address for column jcol) ---
    const int jcol = jt * 16 + nloc;          // 0..111
    const int kt_h = jcol >> 5;
    const int jh   = jcol & 7;
    const int qh16 = ((jcol >> 3) & 3) * 16;  // lane' = b + qh16

    // --- x loader mapping (wave 0): b = u>>2, c = 4*(u&3) ---
    const int xb = u >> 2;
    const int xc = (u & 3) * 4;
    const size_t xbase = (size_t)(b0 + (xb & 15)) * (T_LEN * C_IN) + xc;
    const int jx0 = HH + xc;                  // 112..124
    const int ltx = (xb & 15) + 16 * ((jx0 >> 3) & 3);
    const int jx  = jx0 & 7;

    float4 xreg;
    if (wv == 0) {
        xreg = *(const float4*)&x[xbase];     // x at t=0 -> plane 0
        half4v xh, xl;
        #pragma unroll
        for (int jj = 0; jj < 4; ++jj) {
            _Float16 th, tl;
            split16(((const float*)&xreg)[jj], th, tl);
            xh[jj] = th; xl[jj] = tl;
        }
        *(half4v*)&vbuf[0][0][3][ltx][jx] = xh;
        *(half4v*)&vbuf[0][1][3][ltx][jx] = xl;
    }
    __syncthreads();

    float creg[4] = {0.f, 0.f, 0.f, 0.f};

    #pragma unroll 2
    for (int step = 0; step < T_LEN; ++step) {
        const int p = step & 1;
        if (wv == 0 && step + 1 < T_LEN)
            xreg = *(const float4*)&x[xbase + (size_t)(step + 1) * C_IN];

        f32x4 ch0 = {0.f,0.f,0.f,0.f}, cl0 = {0.f,0.f,0.f,0.f};
        f32x4 ch1 = {0.f,0.f,0.f,0.f}, cl1 = {0.f,0.f,0.f,0.f};
        #pragma unroll
        for (int kt = 0; kt < 4; ++kt) {
            half8 ah = *(const half8*)&vbuf[p][0][kt][lane][0];
            half8 al = *(const half8*)&vbuf[p][1][kt][lane][0];
            ch0 = __builtin_amdgcn_mfma_f32_16x16x32_f16(ah, wHI[0][kt], ch0, 0, 0, 0);
            cl0 = __builtin_amdgcn_mfma_f32_16x16x32_f16(al, wHI[0][kt], cl0, 0, 0, 0);
            cl0 = __builtin_amdgcn_mfma_f32_16x16x32_f16(ah, wLO[0][kt], cl0, 0, 0, 0);
            ch1 = __builtin_amdgcn_mfma_f32_16x16x32_f16(ah, wHI[1][kt], ch1, 0, 0, 0);
            cl1 = __builtin_amdgcn_mfma_f32_16x16x32_f16(al, wHI[1][kt], cl1, 0, 0, 0);
            cl1 = __builtin_amdgcn_mfma_f32_16x16x32_f16(ah, wLO[1][kt], cl1, 0, 0, 0);
        }

        const bool last = (step + 1 == T_LEN);
        if (wlow) {
            // gates: a0 = sigmoid(z_i), a1 = tanh(z_g); publish p = i*g
            f32x4 pp;
            #pragma unroll
            for (int r = 0; r < 4; ++r) {
                float aa = fmaf(ch0[r], -L2E, bpre[0]);
                aa = fmaf(cl0[r], -L2E * (1.f / 4096.f), aa);
                const float a0 = __builtin_amdgcn_rcpf(1.f + __builtin_amdgcn_exp2f(aa));
                float bb = fmaf(ch1[r], -2.f * L2E, bpre[1]);
                bb = fmaf(cl1[r], -2.f * L2E * (1.f / 4096.f), bb);
                const float a1 = fmaf(2.f, __builtin_amdgcn_rcpf(1.f + __builtin_amdgcn_exp2f(bb)), -1.f);
                pp[r] = a0 * a1;
            }
            *(f32x4*)&pbuf[jt][lane][0] = pp;
            __threadfence_block();                 // pp committed before flag
            if (lane == 0) sflag[jt] = step + 1;
            if (wv == 0 && step + 1 < T_LEN) {
                half4v xh, xl;
                #pragma unroll
                for (int jj = 0; jj < 4; ++jj) {
                    _Float16 th, tl;
                    split16(((const float*)&xreg)[jj], th, tl);
                    xh[jj] = th; xl[jj] = tl;
                }
                *(half4v*)&vbuf[1 - p][0][3][ltx][jx] = xh;
                *(half4v*)&vbuf[1 - p][1][3][ltx][jx] = xl;
            }
        } else {
            // gates: a0 = sigmoid(z_f), a1 = sigmoid(z_o)
            float a0[4], a1[4];
            #pragma unroll
            for (int r = 0; r < 4; ++r) {
                float aa = fmaf(ch0[r], -L2E, bpre[0]);
                aa = fmaf(cl0[r], -L2E * (1.f / 4096.f), aa);
                a0[r] = __builtin_amdgcn_rcpf(1.f + __builtin_amdgcn_exp2f(aa));
                float bb = fmaf(ch1[r], -L2E, bpre[1]);
                bb = fmaf(cl1[r], -L2E * (1.f / 4096.f), bb);
                a1[r] = __builtin_amdgcn_rcpf(1.f + __builtin_amdgcn_exp2f(bb));
            }
            while (sflag[jt] < step + 1) { }       // wait for partner's i*g
            __threadfence_block();
            f32x4 pp = *(const f32x4*)&pbuf[jt][lane][0];
            #pragma unroll
            for (int r = 0; r < 4; ++r) {
                const float cn = fmaf(a0[r], creg[r], pp[r]);   // f*c + i*g
                creg[r] = cn;
                const float e2 = __builtin_amdgcn_exp2f(cn * (-2.f * L2E));
                const float th = fmaf(2.f, __builtin_amdgcn_rcpf(1.f + e2), -1.f);
                const float hv = a1[r] * th;                    // o * tanh(c)
                if (!last) {
                    _Float16 hh, hl;
                    split16(hv, hh, hl);
                    vbuf[1 - p][0][kt_h][q * 4 + r + qh16][jh] = hh;
                    vbuf[1 - p][1][kt_h][q * 4 + r + qh16][jh] = hl;
                } else {
                    hfinal[q * 4 + r][jcol] = hv;
                }
            }
        }
        __syncthreads();
    }

    // --- FC head ---
    if (u < NB * 6) {
        const int b = u / 6, o = u - b * 6;
        float a = b_fc[o];
        for (int j = 0; j < HH; ++j) a += hfinal[b][j] * W_fc[o * HH + j];
        out[(size_t)(b0 + b) * 6 + o] = tanhf(a);
    }
}

extern "C" void kernel_launch(void* const* d_in, const int* in_sizes, int n_in,
                              void* d_out, int out_size, void* d_ws, size_t ws_size,
                              hipStream_t stream) {
    const float* x     = (const float*)d_in[0];
    const float* gamma = (const float*)d_in[1];
    const float* beta  = (const float*)d_in[2];
    const float* W_ih  = (const float*)d_in[3];
    const float* W_hh  = (const float*)d_in[4];
    const float* b_ih  = (const float*)d_in[5];
    const float* b_hh  = (const float*)d_in[6];
    const float* W_fc  = (const float*)d_in[7];
    const float* b_fc  = (const float*)d_in[8];
    float* out = (float*)d_out;
    float* ws  = (float*)d_ws;

    stats_kernel<<<SBLK, 256, 0, stream>>>(x, ws);
    lstm_kernel<<<B_TOT / NB, 896, 0, stream>>>(x, gamma, beta, W_ih, W_hh,
                                                b_ih, b_hh, W_fc, b_fc, ws, out);
}